// Round 19
// baseline (261.815 us; speedup 1.0000x reference)
//
#include <hip/hip_runtime.h>
#include <hip/hip_bf16.h>
#include <cstdint>
#include <cstddef>

typedef __attribute__((ext_vector_type(8))) short short8;
typedef __attribute__((ext_vector_type(4))) float f32x4;

#define DEVI static __device__ __forceinline__

DEVI unsigned short f2bf(float f) {
  unsigned u = __float_as_uint(f);
  unsigned r = u + 0x7fffu + ((u >> 16) & 1u);
  return (unsigned short)(r >> 16);
}
DEVI float bf2f(unsigned short s) {
  return __uint_as_float(((unsigned)s) << 16);
}
DEVI unsigned pack2(float a, float b) {
  return (unsigned)f2bf(a) | ((unsigned)f2bf(b) << 16);
}

DEVI void gload16(const void* g, void* l) {
  __builtin_amdgcn_global_load_lds(
      (__attribute__((address_space(1))) void*)g,
      (__attribute__((address_space(3))) void*)l, 16, 0, 0);
}

// counted-vmcnt syncs (T4): exempt only the newest prefetch loads; always
// drain lgkm (LDS visibility). Stage is issued AFTER the barrier (WAR-safe).
#define SYNCA2 do { asm volatile("s_waitcnt vmcnt(2) lgkmcnt(0)" ::: "memory"); __builtin_amdgcn_s_barrier(); } while (0)
#define SYNCA3 do { asm volatile("s_waitcnt vmcnt(3) lgkmcnt(0)" ::: "memory"); __builtin_amdgcn_s_barrier(); } while (0)
#define SYNCA0 do { asm volatile("s_waitcnt vmcnt(0) lgkmcnt(0)" ::: "memory"); __builtin_amdgcn_s_barrier(); } while (0)
#define SYNCB  do { asm volatile("s_waitcnt lgkmcnt(0)" ::: "memory"); __builtin_amdgcn_s_barrier(); } while (0)

// ---------------------------------------------------------------------------
// prep_w: Wq/Wkv -> wcat bf16 [768][256], Wproj -> wpb bf16 [256][256]
// ---------------------------------------------------------------------------
__global__ __launch_bounds__(256) void prep_w(
    const float* __restrict__ Wq, const float* __restrict__ Wkv,
    const float* __restrict__ Wp, unsigned short* __restrict__ wcat,
    unsigned short* __restrict__ wpb) {
  int i = blockIdx.x * 256 + threadIdx.x;
  if (i < 196608) {
    float v = (i < 65536) ? Wq[i] : Wkv[i - 65536];
    wcat[i] = f2bf(v);
  } else {
    int j = i - 196608;
    wpb[j] = f2bf(Wp[j]);
  }
}

// ---------------------------------------------------------------------------
// qkv_ctx v5 = round-16 structure + T4 counted-vmcnt pipeline:
// ring-3 W buffers (3x16KB), raw s_barrier with counted vmcnt (never 0 in
// steady state), stages issued post-barrier. LDS 64KB -> 2 blocks/CU.
// Unified sliver order s=0..23 (Q 0..7, K/V pairs 8..23), stage(s+2) at
// iter s. Two barriers per K iter (BARRIER_B = lgkm-only, loads fly across).
// ---------------------------------------------------------------------------
__global__ __launch_bounds__(512, 4) void qkv_ctx(
    const float* __restrict__ x, const unsigned short* __restrict__ wcat,
    unsigned short* __restrict__ Q, float* __restrict__ pctx,
    float* __restrict__ pksum) {
  const int t = threadIdx.x;
  const int lane = t & 63, w = t >> 6;  // 8 waves
  const int wr = w >> 1, wc = w & 1;    // 4 x 2
  const int blk = blockIdx.x;           // 1024 blocks of 128 rows
  const size_t row0 = (size_t)blk * 128;
  const int fr = lane & 15, fq = lane >> 4;

  __shared__ __align__(16) unsigned char smem[65536];
  unsigned char* const kT = smem + 49152;  // 8KB [32 d][256B] ^((d&7)<<4)
  unsigned char* const vT = smem + 57344;  // 8KB

  const short ob = (short)0x3F80;
  const short8 ones = {ob, ob, ob, ob, ob, ob, ob, ob};

  // ---- x fragments direct to registers: rows wr*32 + i*16 + fr ----
  short8 xfc[2][8];
#pragma unroll
  for (int i = 0; i < 2; ++i) {
    const float* xr = x + (row0 + wr * 32 + i * 16 + fr) * 256;
#pragma unroll
    for (int ks = 0; ks < 8; ++ks) {
      float4 a = *(const float4*)(xr + ks * 32 + fq * 8);
      float4 b2 = *(const float4*)(xr + ks * 32 + fq * 8 + 4);
      union { unsigned u[4]; short8 s; } cv;
      cv.u[0] = pack2(a.x, a.y);
      cv.u[1] = pack2(a.z, a.w);
      cv.u[2] = pack2(b2.x, b2.y);
      cv.u[3] = pack2(b2.z, b2.w);
      xfc[i][ks] = cv.s;
    }
  }

  const int segr = lane >> 5;
  const int segc = (lane & 31) * 16;
  auto stage_w = [&](unsigned char* buf, int s) {
    int wr0 = (s < 8) ? s * 32
                      : (((s & 1) == 0) ? 256 + ((s - 8) >> 1) * 32
                                        : 512 + ((s - 8) >> 1) * 32);
#pragma unroll
    for (int i = 0; i < 2; ++i) {
      int seg = w * 2 + i;
      int rloc = seg * 2 + segr;
      gload16((const char*)wcat + (size_t)(wr0 + rloc) * 512 +
                  (segc ^ ((rloc & 7) << 4)),
              buf + seg * 1024);
    }
  };

  // ctx: waves 0-3 (dp = w>>1, ep = w&1); 4 ks steps over 128 n
  auto ctx_head = [&](int h) {
    if (w < 4) {
      const int dp = w >> 1, ep = w & 1;
      f32x4 cacc = {0.f, 0.f, 0.f, 0.f};
      const int rka = dp * 16 + fr;
      const int rkb = ep * 16 + fr;
#pragma unroll
      for (int ks = 0; ks < 4; ++ks) {
        short8 ak = *(const short8*)(kT + rka * 256 +
                                     ((ks * 64 + fq * 16) ^ ((rka & 7) << 4)));
        short8 bv = *(const short8*)(vT + rkb * 256 +
                                     ((ks * 64 + fq * 16) ^ ((rkb & 7) << 4)));
        cacc = __builtin_amdgcn_mfma_f32_16x16x32_bf16(ak, bv, cacc, 0, 0, 0);
      }
      float* pc = pctx + ((size_t)(blk * 8 + h)) * 1024;
#pragma unroll
      for (int reg = 0; reg < 4; ++reg) {
        int d = dp * 16 + fq * 4 + reg;
        int e = ep * 16 + fr;
        pc[d * 32 + e] = cacc[reg];
      }
    }
  };

  // ksum: waves 4-5 (dp = w&1), ones-MFMA on kT
  auto ksum_head = [&](int h) {
    if ((w >> 1) == 2) {
      const int dp = w & 1;
      f32x4 sacc = {0.f, 0.f, 0.f, 0.f};
      const int rka = dp * 16 + fr;
#pragma unroll
      for (int ks = 0; ks < 4; ++ks) {
        short8 ak = *(const short8*)(kT + rka * 256 +
                                     ((ks * 64 + fq * 16) ^ ((rka & 7) << 4)));
        sacc = __builtin_amdgcn_mfma_f32_16x16x32_bf16(ak, ones, sacc, 0, 0, 0);
      }
      if (fr == 0) {
#pragma unroll
        for (int reg = 0; reg < 4; ++reg) {
          int d = dp * 16 + fq * 4 + reg;
          pksum[((size_t)(blk * 8 + h)) * 32 + d] = sacc[reg];
        }
      }
    }
  };

  // prologue: stage slivers 0,1 (ring buffers 0,1)
  stage_w(smem, 0);
  stage_w(smem + 16384, 1);

  unsigned char* const bb = kT + w * 1536;  // wave-private bounce [32][48B]

  // ================= Q phase: slivers 0..7 =================
#pragma unroll
  for (int s = 0; s < 8; ++s) {
    if (s == 0) { SYNCA2; } else { SYNCA3; }   // exempt newest prefetch(+store)
    stage_w(smem + ((s + 2) % 3) * 16384, s + 2);
    const unsigned char* wbuf = smem + (s % 3) * 16384;

    f32x4 acc[2] = {{0.f, 0.f, 0.f, 0.f}, {0.f, 0.f, 0.f, 0.f}};
    const int rb = wc * 16 + fr;
    const int swb = (rb & 7) << 4;
#pragma unroll
    for (int ks = 0; ks < 8; ++ks) {
      short8 wf = *(const short8*)(wbuf + rb * 512 + ((ks * 64 + fq * 16) ^ swb));
      acc[0] = __builtin_amdgcn_mfma_f32_16x16x32_bf16(wf, xfc[0][ks], acc[0], 0, 0, 0);
      acc[1] = __builtin_amdgcn_mfma_f32_16x16x32_bf16(wf, xfc[1][ks], acc[1], 0, 0, 0);
    }
    // lane holds Q[x-row wr*32+i*16+fr][col s*32 + wc*16 + fq*4 + 0..3]
#pragma unroll
    for (int i = 0; i < 2; ++i) {
      float v0 = acc[i][0], v1 = acc[i][1], v2 = acc[i][2], v3 = acc[i][3];
      v0 = (v0 > 0.f) ? (v0 + 1.f) : __expf(v0);
      v1 = (v1 > 0.f) ? (v1 + 1.f) : __expf(v1);
      v2 = (v2 > 0.f) ? (v2 + 1.f) : __expf(v2);
      v3 = (v3 > 0.f) ? (v3 + 1.f) : __expf(v3);
      uint2 pk;
      pk.x = pack2(v0, v1);
      pk.y = pack2(v2, v3);
      *(uint2*)(bb + (i * 16 + fr) * 48 + fq * 8) = pk;
    }
    {
      int rowq = lane >> 1, ch = lane & 1;
      uint4 u = *(const uint4*)(bb + rowq * 48 + ch * 16);
      *(uint4*)((char*)Q + (row0 + wr * 32 + rowq) * 512 + s * 64 + wc * 32 +
                ch * 16) = u;
    }
  }

  // ================= K/V phase: heads 0..7 =================
#pragma unroll
  for (int h = 0; h < 8; ++h) {
    const int sk = 8 + 2 * h, sv = sk + 1;
    // ---- K iteration (consume wb[sk%3]) ----
    if (h == 0) { SYNCA3; } else { SYNCA2; }
    if (sk + 2 < 24) stage_w(smem + ((sk + 2) % 3) * 16384, sk + 2);
    f32x4 kacc[2] = {{0.f, 0.f, 0.f, 0.f}, {0.f, 0.f, 0.f, 0.f}};
    {
      const unsigned char* wbuf = smem + (sk % 3) * 16384;
      const int rb = wc * 16 + fr;
      const int swb = (rb & 7) << 4;
#pragma unroll
      for (int ks = 0; ks < 8; ++ks) {
        short8 wf = *(const short8*)(wbuf + rb * 512 + ((ks * 64 + fq * 16) ^ swb));
        kacc[0] = __builtin_amdgcn_mfma_f32_16x16x32_bf16(xfc[0][ks], wf, kacc[0], 0, 0, 0);
        kacc[1] = __builtin_amdgcn_mfma_f32_16x16x32_bf16(xfc[1][ks], wf, kacc[1], 0, 0, 0);
      }
    }
    if (h > 0) {
      ctx_head(h - 1);   // waves 0-3: reads kT/vT of head h-1
      ksum_head(h - 1);  // waves 4-5: reads kT of head h-1
    }
    SYNCB;  // readers of kT/vT(h-1) retired; prefetch loads stay in flight

    // kT write: d = wc*16+fr, n = wr*32 + i*16 + fq*4 + 0..3 (elu)
#pragma unroll
    for (int i = 0; i < 2; ++i) {
      int d = wc * 16 + fr;
      float v0 = kacc[i][0], v1 = kacc[i][1], v2 = kacc[i][2], v3 = kacc[i][3];
      v0 = (v0 > 0.f) ? (v0 + 1.f) : __expf(v0);
      v1 = (v1 > 0.f) ? (v1 + 1.f) : __expf(v1);
      v2 = (v2 > 0.f) ? (v2 + 1.f) : __expf(v2);
      v3 = (v3 > 0.f) ? (v3 + 1.f) : __expf(v3);
      uint2 pk;
      pk.x = pack2(v0, v1);
      pk.y = pack2(v2, v3);
      int nb = wr * 64 + i * 32 + fq * 8;  // byte offset = n*2
      *(uint2*)(kT + d * 256 + (nb ^ ((d & 7) << 4))) = pk;
    }

    // ---- V iteration (consume wb[sv%3]) ----
    if (sv + 2 < 24) {
      SYNCA2;
      stage_w(smem + ((sv + 2) % 3) * 16384, sv + 2);
    } else {
      SYNCA0;
    }
    f32x4 vacc[2] = {{0.f, 0.f, 0.f, 0.f}, {0.f, 0.f, 0.f, 0.f}};
    {
      const unsigned char* wbuf = smem + (sv % 3) * 16384;
      const int rb = wc * 16 + fr;
      const int swb = (rb & 7) << 4;
#pragma unroll
      for (int ks = 0; ks < 8; ++ks) {
        short8 wf = *(const short8*)(wbuf + rb * 512 + ((ks * 64 + fq * 16) ^ swb));
        vacc[0] = __builtin_amdgcn_mfma_f32_16x16x32_bf16(xfc[0][ks], wf, vacc[0], 0, 0, 0);
        vacc[1] = __builtin_amdgcn_mfma_f32_16x16x32_bf16(xfc[1][ks], wf, vacc[1], 0, 0, 0);
      }
    }
    // vT write: ctx readers of vT(h-1) retired at this head's SYNCB
#pragma unroll
    for (int i = 0; i < 2; ++i) {
      int e = wc * 16 + fr;
      uint2 pk;
      pk.x = pack2(vacc[i][0], vacc[i][1]);
      pk.y = pack2(vacc[i][2], vacc[i][3]);
      int nb = wr * 64 + i * 32 + fq * 8;
      *(uint2*)(vT + e * 256 + (nb ^ ((e & 7) << 4))) = pk;
    }
  }
  SYNCB;  // kT/vT(7) visible
  ctx_head(7);
  ksum_head(7);
}

// ---------------------------------------------------------------------------
// ctx_final2: reduce 128 block-partials per (b,h) -> ctxT bf16 hi/lo + ksum
// ---------------------------------------------------------------------------
__global__ __launch_bounds__(256) void ctx_final2(
    const float* __restrict__ pctx, const float* __restrict__ pksum,
    unsigned short* __restrict__ ctxT, float* __restrict__ ksum) {
  int bh = blockIdx.x;
  int b = bh >> 3, h = bh & 7;
  int t = threadIdx.x;
  int d = t >> 3, e4 = (t & 7) * 4;
  float s[4] = {0.f, 0.f, 0.f, 0.f};
  for (int pp = 0; pp < 128; ++pp) {
    const float* q = pctx + ((size_t)((b * 128 + pp) * 8 + h)) * 1024 + d * 32 + e4;
    s[0] += q[0]; s[1] += q[1]; s[2] += q[2]; s[3] += q[3];
  }
  unsigned short* cc = ctxT + (size_t)bh * 2048;
#pragma unroll
  for (int e2 = 0; e2 < 4; ++e2) {
    int e = e4 + e2;
    unsigned short hi = f2bf(s[e2]);
    float lo = s[e2] - bf2f(hi);
    cc[e * 32 + d] = hi;
    cc[1024 + e * 32 + d] = f2bf(lo);
  }
  __shared__ float ksp[8][32];
  int d2 = t & 31, ch = t >> 5;
  float ss = 0.f;
  for (int pp = ch; pp < 128; pp += 8)
    ss += pksum[((size_t)((b * 128 + pp) * 8 + h)) * 32 + d2];
  ksp[ch][d2] = ss;
  __syncthreads();
  if (t < 32) {
    float r = 0.f;
#pragma unroll
    for (int c = 0; c < 8; ++c) r += ksp[c][t];
    ksum[bh * 32 + t] = r;
  }
}

// ---------------------------------------------------------------------------
// attn_proj (round-12/13 proven, unchanged): 2048 blocks (64-row panels),
// 512 thr, 68.6KB LDS -> 2 blocks/CU.
// ---------------------------------------------------------------------------
__global__ __launch_bounds__(512) void attn_proj(
    const unsigned short* __restrict__ Q,
    const unsigned short* __restrict__ ctxT,
    const float* __restrict__ ksum,
    const unsigned short* __restrict__ wpb,
    const float* __restrict__ bias,
    float* __restrict__ out) {
  const int t = threadIdx.x;
  const int lane = t & 63, w = t >> 6;  // 8 waves
  const int panel = blockIdx.x;         // 2048
  const int b = panel >> 8;
  const size_t row0 = (size_t)panel * 64;
  const int fr = lane & 15, fq = lane >> 4;

  __shared__ __align__(16) unsigned char qa[32768];      // [64][512B] swz
  __shared__ __align__(16) unsigned char wpS[2][16384];  // ping-pong W stages
  __shared__ float ksumL[256];
  __shared__ float Dinv_s[64][8];

#pragma unroll
  for (int s = 0; s < 4; ++s) {
    int seg = w * 4 + s;
    int row = seg * 2 + (lane >> 5);
    gload16((const char*)Q + (row0 + row) * 512 +
                (((lane & 31) * 16) ^ ((row & 7) << 4)),
            qa + seg * 1024);
  }
  if (w == 0) gload16((const char*)(ksum + b * 256) + lane * 16, (void*)ksumL);
  __syncthreads();

  {
    int r = t >> 3, h = t & 7;
    const unsigned char* qrow = qa + r * 512;
    int swzr = (r & 7) << 4;
    float s = 0.f;
#pragma unroll
    for (int dd = 0; dd < 16; ++dd) {
      unsigned u = *(const unsigned*)(qrow + ((h * 64 + dd * 4) ^ swzr));
      s += __uint_as_float(u << 16) * ksumL[h * 32 + dd * 2] +
           __uint_as_float(u & 0xffff0000u) * ksumL[h * 32 + dd * 2 + 1];
    }
    Dinv_s[r][h] = 1.f / fmaxf(s, 1e-6f);
  }

  const int rg = w >> 2, hg = w & 3;
  f32x4 sacc[2][2][2];
#pragma unroll
  for (int h2 = 0; h2 < 2; ++h2)
#pragma unroll
    for (int i = 0; i < 2; ++i)
#pragma unroll
      for (int j = 0; j < 2; ++j)
#pragma unroll
        for (int c = 0; c < 4; ++c) sacc[h2][i][j][c] = 0.f;

#pragma unroll
  for (int h2 = 0; h2 < 2; ++h2) {
    int h = hg * 2 + h2;
    const char* cbh = (const char*)ctxT + ((size_t)(b * 8 + h)) * 4096;
    short8 bhi[2], blo[2];
#pragma unroll
    for (int j = 0; j < 2; ++j) {
      int e = j * 16 + fr;
      bhi[j] = *(const short8*)(cbh + e * 64 + fq * 16);
      blo[j] = *(const short8*)(cbh + 2048 + e * 64 + fq * 16);
    }
#pragma unroll
    for (int i = 0; i < 2; ++i) {
      int ra = rg * 32 + i * 16 + fr;
      short8 af = *(const short8*)(qa + ra * 512 +
                                   ((h * 64 + fq * 16) ^ ((ra & 7) << 4)));
#pragma unroll
      for (int j = 0; j < 2; ++j) {
        sacc[h2][i][j] = __builtin_amdgcn_mfma_f32_16x16x32_bf16(
            af, bhi[j], sacc[h2][i][j], 0, 0, 0);
        sacc[h2][i][j] = __builtin_amdgcn_mfma_f32_16x16x32_bf16(
            af, blo[j], sacc[h2][i][j], 0, 0, 0);
      }
    }
  }
  __syncthreads();

#pragma unroll
  for (int h2 = 0; h2 < 2; ++h2) {
    int h = hg * 2 + h2;
#pragma unroll
    for (int i = 0; i < 2; ++i)
#pragma unroll
      for (int j = 0; j < 2; ++j)
#pragma unroll
        for (int reg = 0; reg < 4; ++reg) {
          int r = rg * 32 + i * 16 + fq * 4 + reg;
          int e = j * 16 + fr;
          float v = sacc[h2][i][j][reg] * Dinv_s[r][h];
          *(unsigned short*)(qa + r * 512 +
                             ((h * 64 + e * 2) ^ ((r & 7) << 4))) = f2bf(v);
        }
  }

  auto stage_wp = [&](int q, unsigned char* buf) {
#pragma unroll
    for (int i = 0; i < 2; ++i) {
      int seg = w * 2 + i;
      int rloc = seg * 2 + (lane >> 5);
      gload16((const char*)wpb + (size_t)(q * 32 + rloc) * 512 +
                  (((lane & 31) * 16) ^ ((rloc & 7) << 4)),
              buf + seg * 1024);
    }
  };
  stage_wp(0, wpS[0]);
  __syncthreads();

  const int rw = w >> 1, cw = w & 1;
  const int ra2 = rw * 16 + fr;
  const int sra2 = (ra2 & 7) << 4;
  for (int q = 0; q < 8; ++q) {
    if (q < 7) stage_wp(q + 1, wpS[(q + 1) & 1]);
    const unsigned char* wbuf = wpS[q & 1];
    f32x4 oacc = {0.f, 0.f, 0.f, 0.f};
#pragma unroll
    for (int ks = 0; ks < 8; ++ks) {
      short8 af = *(const short8*)(qa + ra2 * 512 + ((ks * 64 + fq * 16) ^ sra2));
      int rb = cw * 16 + fr;
      short8 wf = *(const short8*)(wbuf + rb * 512 +
                                   ((ks * 64 + fq * 16) ^ ((rb & 7) << 4)));
      oacc = __builtin_amdgcn_mfma_f32_16x16x32_bf16(af, wf, oacc, 0, 0, 0);
    }
    float bj = bias[q * 32 + cw * 16 + fr];
    float* orow = out + row0 * 256 + (size_t)(rw * 16 + fq * 4) * 256 +
                  q * 32 + cw * 16 + fr;
#pragma unroll
    for (int reg = 0; reg < 4; ++reg) orow[reg * 256] = oacc[reg] + bj;
    __syncthreads();
  }
}

// ---------------------------------------------------------------------------
extern "C" void kernel_launch(void* const* d_in, const int* in_sizes, int n_in,
                              void* d_out, int out_size, void* d_ws, size_t ws_size,
                              hipStream_t stream) {
  const float* x = (const float*)d_in[0];
  const float* Wq = (const float*)d_in[1];
  const float* Wkv = (const float*)d_in[2];
  const float* Wproj = (const float*)d_in[3];
  const float* bproj = (const float*)d_in[4];
  float* out = (float*)d_out;

  char* ws = (char*)d_ws;
  unsigned short* Q = (unsigned short*)(ws);                  // 67,108,864
  unsigned short* wcat = (unsigned short*)(ws + 67108864);    // 393,216
  unsigned short* wpb = (unsigned short*)(ws + 67502080);     // 131,072
  float* pctx = (float*)(ws + 67633152);                      // 33,554,432
  float* pksum = (float*)(ws + 101187584);                    // 1,048,576
  unsigned short* ctxT = (unsigned short*)(ws + 102236160);   // 262,144
  float* ksum = (float*)(ws + 102498304);                     // 8,192

  prep_w<<<1024, 256, 0, stream>>>(Wq, Wkv, Wproj, wcat, wpb);
  qkv_ctx<<<1024, 512, 0, stream>>>(x, wcat, Q, pctx, pksum);
  ctx_final2<<<64, 256, 0, stream>>>(pctx, pksum, ctxT, ksum);
  attn_proj<<<2048, 512, 0, stream>>>(Q, ctxT, ksum, wpb, bproj, out);
}

// Round 20
// 173.760 us; speedup vs baseline: 1.5068x; 1.5068x over previous
//
#include <hip/hip_runtime.h>
#include <hip/hip_bf16.h>
#include <cstdint>
#include <cstddef>

typedef __attribute__((ext_vector_type(8))) short short8;
typedef __attribute__((ext_vector_type(4))) float f32x4;

#define DEVI static __device__ __forceinline__

DEVI unsigned short f2bf(float f) {
  unsigned u = __float_as_uint(f);
  unsigned r = u + 0x7fffu + ((u >> 16) & 1u);
  return (unsigned short)(r >> 16);
}
DEVI float bf2f(unsigned short s) {
  return __uint_as_float(((unsigned)s) << 16);
}
DEVI unsigned pack2(float a, float b) {
  return (unsigned)f2bf(a) | ((unsigned)f2bf(b) << 16);
}

DEVI void gload16(const void* g, void* l) {
  __builtin_amdgcn_global_load_lds(
      (__attribute__((address_space(1))) void*)g,
      (__attribute__((address_space(3))) void*)l, 16, 0, 0);
}

// ---------------------------------------------------------------------------
// prep_w: Wq/Wkv -> wcat bf16 [768][256], Wproj -> wpb bf16 [256][256]
// ---------------------------------------------------------------------------
__global__ __launch_bounds__(256) void prep_w(
    const float* __restrict__ Wq, const float* __restrict__ Wkv,
    const float* __restrict__ Wp, unsigned short* __restrict__ wcat,
    unsigned short* __restrict__ wpb) {
  int i = blockIdx.x * 256 + threadIdx.x;
  if (i < 196608) {
    float v = (i < 65536) ? Wq[i] : Wkv[i - 65536];
    wcat[i] = f2bf(v);
  } else {
    int j = i - 196608;
    wpb[j] = f2bf(Wp[j]);
  }
}

// ---------------------------------------------------------------------------
// qkv_ctx v4.3 (round-16/18 proven, 113 us): 1024 blocks x 512 thr (8 waves =
// 4 row-groups x 2 col-groups), 128 rows/block. xfc[2][8] per wave.
// 24 W-slivers (32 rows) ping-pong gload_lds; K/V phase 2 barriers/head;
// ksum on waves 4-5. LDS 48KB. VGPR cap 128 (launch_bounds 512,4) -> 64 used.
// Lessons encoded: (512,6) -> VGPR 40 spill 4x slower (r17); source-level
// counted-vmcnt -> compiler spill/remat, 1.8x slower (r19); inline cvt_pk
// asm -> NaN (r14). This 2-barrier __syncthreads schedule is the plain-HIP
// floor for this structure.
// ---------------------------------------------------------------------------
__global__ __launch_bounds__(512, 4) void qkv_ctx(
    const float* __restrict__ x, const unsigned short* __restrict__ wcat,
    unsigned short* __restrict__ Q, float* __restrict__ pctx,
    float* __restrict__ pksum) {
  const int t = threadIdx.x;
  const int lane = t & 63, w = t >> 6;  // 8 waves
  const int wr = w >> 1, wc = w & 1;    // 4 x 2
  const int blk = blockIdx.x;           // 1024 blocks of 128 rows
  const size_t row0 = (size_t)blk * 128;
  const int fr = lane & 15, fq = lane >> 4;

  __shared__ __align__(16) unsigned char smem[49152];
  unsigned char* const wb0 = smem;           // 16KB [32][512B]
  unsigned char* const wb1 = smem + 16384;   // 16KB
  unsigned char* const kT = smem + 32768;    // 8KB [32 d][256B] ^((d&7)<<4)
  unsigned char* const vT = smem + 40960;    // 8KB

  const short ob = (short)0x3F80;
  const short8 ones = {ob, ob, ob, ob, ob, ob, ob, ob};

  // ---- x fragments direct to registers: rows wr*32 + i*16 + fr ----
  short8 xfc[2][8];
#pragma unroll
  for (int i = 0; i < 2; ++i) {
    const float* xr = x + (row0 + wr * 32 + i * 16 + fr) * 256;
#pragma unroll
    for (int ks = 0; ks < 8; ++ks) {
      float4 a = *(const float4*)(xr + ks * 32 + fq * 8);
      float4 b2 = *(const float4*)(xr + ks * 32 + fq * 8 + 4);
      union { unsigned u[4]; short8 s; } cv;
      cv.u[0] = pack2(a.x, a.y);
      cv.u[1] = pack2(a.z, a.w);
      cv.u[2] = pack2(b2.x, b2.y);
      cv.u[3] = pack2(b2.z, b2.w);
      xfc[i][ks] = cv.s;
    }
  }

  const int segr = lane >> 5;
  const int segc = (lane & 31) * 16;
  auto stage_w = [&](unsigned char* buf, int s) {
    int wr0 = (s < 8) ? s * 32
                      : (((s & 1) == 0) ? 256 + ((s - 8) >> 1) * 32
                                        : 512 + ((s - 8) >> 1) * 32);
#pragma unroll
    for (int i = 0; i < 2; ++i) {
      int seg = w * 2 + i;
      int rloc = seg * 2 + segr;
      gload16((const char*)wcat + (size_t)(wr0 + rloc) * 512 +
                  (segc ^ ((rloc & 7) << 4)),
              buf + seg * 1024);
    }
  };

  // ctx: waves 0-3 (dp = w>>1, ep = w&1); 4 ks steps over 128 n
  auto ctx_head = [&](int h) {
    if (w < 4) {
      const int dp = w >> 1, ep = w & 1;
      f32x4 cacc = {0.f, 0.f, 0.f, 0.f};
      const int rka = dp * 16 + fr;
      const int rkb = ep * 16 + fr;
#pragma unroll
      for (int ks = 0; ks < 4; ++ks) {
        short8 ak = *(const short8*)(kT + rka * 256 +
                                     ((ks * 64 + fq * 16) ^ ((rka & 7) << 4)));
        short8 bv = *(const short8*)(vT + rkb * 256 +
                                     ((ks * 64 + fq * 16) ^ ((rkb & 7) << 4)));
        cacc = __builtin_amdgcn_mfma_f32_16x16x32_bf16(ak, bv, cacc, 0, 0, 0);
      }
      float* pc = pctx + ((size_t)(blk * 8 + h)) * 1024;
#pragma unroll
      for (int reg = 0; reg < 4; ++reg) {
        int d = dp * 16 + fq * 4 + reg;
        int e = ep * 16 + fr;
        pc[d * 32 + e] = cacc[reg];
      }
    }
  };

  // ksum: waves 4-5 (dp = w&1), ones-MFMA on kT
  auto ksum_head = [&](int h) {
    if ((w >> 1) == 2) {
      const int dp = w & 1;
      f32x4 sacc = {0.f, 0.f, 0.f, 0.f};
      const int rka = dp * 16 + fr;
#pragma unroll
      for (int ks = 0; ks < 4; ++ks) {
        short8 ak = *(const short8*)(kT + rka * 256 +
                                     ((ks * 64 + fq * 16) ^ ((rka & 7) << 4)));
        sacc = __builtin_amdgcn_mfma_f32_16x16x32_bf16(ak, ones, sacc, 0, 0, 0);
      }
      if (fr == 0) {
#pragma unroll
        for (int reg = 0; reg < 4; ++reg) {
          int d = dp * 16 + fq * 4 + reg;
          pksum[((size_t)(blk * 8 + h)) * 32 + d] = sacc[reg];
        }
      }
    }
  };

  stage_w(wb0, 0);
  __syncthreads();

  unsigned char* const bb = kT + w * 1536;  // wave-private bounce [32][48B]

  // ================= Q phase: slivers 0..7 =================
#pragma unroll
  for (int s = 0; s < 8; ++s) {
    stage_w((s & 1) ? wb0 : wb1, s + 1);
    const unsigned char* wbuf = (s & 1) ? wb1 : wb0;

    f32x4 acc[2] = {{0.f, 0.f, 0.f, 0.f}, {0.f, 0.f, 0.f, 0.f}};
    const int rb = wc * 16 + fr;
    const int swb = (rb & 7) << 4;
#pragma unroll
    for (int ks = 0; ks < 8; ++ks) {
      short8 wf = *(const short8*)(wbuf + rb * 512 + ((ks * 64 + fq * 16) ^ swb));
      acc[0] = __builtin_amdgcn_mfma_f32_16x16x32_bf16(wf, xfc[0][ks], acc[0], 0, 0, 0);
      acc[1] = __builtin_amdgcn_mfma_f32_16x16x32_bf16(wf, xfc[1][ks], acc[1], 0, 0, 0);
    }
    // lane holds Q[x-row wr*32+i*16+fr][col s*32 + wc*16 + fq*4 + 0..3]
#pragma unroll
    for (int i = 0; i < 2; ++i) {
      float v0 = acc[i][0], v1 = acc[i][1], v2 = acc[i][2], v3 = acc[i][3];
      v0 = (v0 > 0.f) ? (v0 + 1.f) : __expf(v0);
      v1 = (v1 > 0.f) ? (v1 + 1.f) : __expf(v1);
      v2 = (v2 > 0.f) ? (v2 + 1.f) : __expf(v2);
      v3 = (v3 > 0.f) ? (v3 + 1.f) : __expf(v3);
      uint2 pk;
      pk.x = pack2(v0, v1);
      pk.y = pack2(v2, v3);
      *(uint2*)(bb + (i * 16 + fr) * 48 + fq * 8) = pk;
    }
    {
      int rowq = lane >> 1, ch = lane & 1;
      uint4 u = *(const uint4*)(bb + rowq * 48 + ch * 16);
      *(uint4*)((char*)Q + (row0 + wr * 32 + rowq) * 512 + s * 64 + wc * 32 +
                ch * 16) = u;
    }
    __syncthreads();
  }

  // ================= K/V phase: heads 0..7 (2 barriers/head) =============
#pragma unroll
  for (int h = 0; h < 8; ++h) {
    const int sk = 8 + 2 * h;
    // ---- K sliver (wb0) ----
    stage_w(wb1, sk + 1);  // V head h
    f32x4 kacc[2] = {{0.f, 0.f, 0.f, 0.f}, {0.f, 0.f, 0.f, 0.f}};
    {
      const int rb = wc * 16 + fr;
      const int swb = (rb & 7) << 4;
#pragma unroll
      for (int ks = 0; ks < 8; ++ks) {
        short8 wf = *(const short8*)(wb0 + rb * 512 + ((ks * 64 + fq * 16) ^ swb));
        kacc[0] = __builtin_amdgcn_mfma_f32_16x16x32_bf16(xfc[0][ks], wf, kacc[0], 0, 0, 0);
        kacc[1] = __builtin_amdgcn_mfma_f32_16x16x32_bf16(xfc[1][ks], wf, kacc[1], 0, 0, 0);
      }
    }
    if (h > 0) {
      ctx_head(h - 1);   // waves 0-3: reads kT/vT of head h-1
      ksum_head(h - 1);  // waves 4-5: reads kT of head h-1
    }
    __syncthreads();  // #1: ctx/ksum reads done; V staged; wb0 reads done

    // kT write: d = wc*16+fr, n = wr*32 + i*16 + fq*4 + 0..3 (elu)
#pragma unroll
    for (int i = 0; i < 2; ++i) {
      int d = wc * 16 + fr;
      float v0 = kacc[i][0], v1 = kacc[i][1], v2 = kacc[i][2], v3 = kacc[i][3];
      v0 = (v0 > 0.f) ? (v0 + 1.f) : __expf(v0);
      v1 = (v1 > 0.f) ? (v1 + 1.f) : __expf(v1);
      v2 = (v2 > 0.f) ? (v2 + 1.f) : __expf(v2);
      v3 = (v3 > 0.f) ? (v3 + 1.f) : __expf(v3);
      uint2 pk;
      pk.x = pack2(v0, v1);
      pk.y = pack2(v2, v3);
      int nb = wr * 64 + i * 32 + fq * 8;  // byte offset = n*2
      *(uint2*)(kT + d * 256 + (nb ^ ((d & 7) << 4))) = pk;
    }

    // ---- V sliver (wb1) ----
    if (h < 7) stage_w(wb0, sk + 2);  // K head h+1
    f32x4 vacc[2] = {{0.f, 0.f, 0.f, 0.f}, {0.f, 0.f, 0.f, 0.f}};
    {
      const int rb = wc * 16 + fr;
      const int swb = (rb & 7) << 4;
#pragma unroll
      for (int ks = 0; ks < 8; ++ks) {
        short8 wf = *(const short8*)(wb1 + rb * 512 + ((ks * 64 + fq * 16) ^ swb));
        vacc[0] = __builtin_amdgcn_mfma_f32_16x16x32_bf16(xfc[0][ks], wf, vacc[0], 0, 0, 0);
        vacc[1] = __builtin_amdgcn_mfma_f32_16x16x32_bf16(xfc[1][ks], wf, vacc[1], 0, 0, 0);
      }
    }
    // vT write: prev readers (ctx_head(h-1)) completed before barrier #1
#pragma unroll
    for (int i = 0; i < 2; ++i) {
      int e = wc * 16 + fr;
      uint2 pk;
      pk.x = pack2(vacc[i][0], vacc[i][1]);
      pk.y = pack2(vacc[i][2], vacc[i][3]);
      int nb = wr * 64 + i * 32 + fq * 8;
      *(uint2*)(vT + e * 256 + (nb ^ ((e & 7) << 4))) = pk;
    }
    __syncthreads();  // #2: kT+vT visible; stages drained
  }
  ctx_head(7);
  ksum_head(7);
}

// ---------------------------------------------------------------------------
// ctx_final2: reduce 128 block-partials per (b,h) -> ctxT bf16 hi/lo + ksum
// ---------------------------------------------------------------------------
__global__ __launch_bounds__(256) void ctx_final2(
    const float* __restrict__ pctx, const float* __restrict__ pksum,
    unsigned short* __restrict__ ctxT, float* __restrict__ ksum) {
  int bh = blockIdx.x;
  int b = bh >> 3, h = bh & 7;
  int t = threadIdx.x;
  int d = t >> 3, e4 = (t & 7) * 4;
  float s[4] = {0.f, 0.f, 0.f, 0.f};
  for (int pp = 0; pp < 128; ++pp) {
    const float* q = pctx + ((size_t)((b * 128 + pp) * 8 + h)) * 1024 + d * 32 + e4;
    s[0] += q[0]; s[1] += q[1]; s[2] += q[2]; s[3] += q[3];
  }
  unsigned short* cc = ctxT + (size_t)bh * 2048;
#pragma unroll
  for (int e2 = 0; e2 < 4; ++e2) {
    int e = e4 + e2;
    unsigned short hi = f2bf(s[e2]);
    float lo = s[e2] - bf2f(hi);
    cc[e * 32 + d] = hi;
    cc[1024 + e * 32 + d] = f2bf(lo);
  }
  __shared__ float ksp[8][32];
  int d2 = t & 31, ch = t >> 5;
  float ss = 0.f;
  for (int pp = ch; pp < 128; pp += 8)
    ss += pksum[((size_t)((b * 128 + pp) * 8 + h)) * 32 + d2];
  ksp[ch][d2] = ss;
  __syncthreads();
  if (t < 32) {
    float r = 0.f;
#pragma unroll
    for (int c = 0; c < 8; ++c) r += ksp[c][t];
    ksum[bh * 32 + t] = r;
  }
}

// ---------------------------------------------------------------------------
// attn_proj (round-12/13 proven, unchanged): 2048 blocks (64-row panels),
// 512 thr, 68.6KB LDS -> 2 blocks/CU.
// ---------------------------------------------------------------------------
__global__ __launch_bounds__(512) void attn_proj(
    const unsigned short* __restrict__ Q,
    const unsigned short* __restrict__ ctxT,
    const float* __restrict__ ksum,
    const unsigned short* __restrict__ wpb,
    const float* __restrict__ bias,
    float* __restrict__ out) {
  const int t = threadIdx.x;
  const int lane = t & 63, w = t >> 6;  // 8 waves
  const int panel = blockIdx.x;         // 2048
  const int b = panel >> 8;
  const size_t row0 = (size_t)panel * 64;
  const int fr = lane & 15, fq = lane >> 4;

  __shared__ __align__(16) unsigned char qa[32768];      // [64][512B] swz
  __shared__ __align__(16) unsigned char wpS[2][16384];  // ping-pong W stages
  __shared__ float ksumL[256];
  __shared__ float Dinv_s[64][8];

#pragma unroll
  for (int s = 0; s < 4; ++s) {
    int seg = w * 4 + s;
    int row = seg * 2 + (lane >> 5);
    gload16((const char*)Q + (row0 + row) * 512 +
                (((lane & 31) * 16) ^ ((row & 7) << 4)),
            qa + seg * 1024);
  }
  if (w == 0) gload16((const char*)(ksum + b * 256) + lane * 16, (void*)ksumL);
  __syncthreads();

  {
    int r = t >> 3, h = t & 7;
    const unsigned char* qrow = qa + r * 512;
    int swzr = (r & 7) << 4;
    float s = 0.f;
#pragma unroll
    for (int dd = 0; dd < 16; ++dd) {
      unsigned u = *(const unsigned*)(qrow + ((h * 64 + dd * 4) ^ swzr));
      s += __uint_as_float(u << 16) * ksumL[h * 32 + dd * 2] +
           __uint_as_float(u & 0xffff0000u) * ksumL[h * 32 + dd * 2 + 1];
    }
    Dinv_s[r][h] = 1.f / fmaxf(s, 1e-6f);
  }

  const int rg = w >> 2, hg = w & 3;
  f32x4 sacc[2][2][2];
#pragma unroll
  for (int h2 = 0; h2 < 2; ++h2)
#pragma unroll
    for (int i = 0; i < 2; ++i)
#pragma unroll
      for (int j = 0; j < 2; ++j)
#pragma unroll
        for (int c = 0; c < 4; ++c) sacc[h2][i][j][c] = 0.f;

#pragma unroll
  for (int h2 = 0; h2 < 2; ++h2) {
    int h = hg * 2 + h2;
    const char* cbh = (const char*)ctxT + ((size_t)(b * 8 + h)) * 4096;
    short8 bhi[2], blo[2];
#pragma unroll
    for (int j = 0; j < 2; ++j) {
      int e = j * 16 + fr;
      bhi[j] = *(const short8*)(cbh + e * 64 + fq * 16);
      blo[j] = *(const short8*)(cbh + 2048 + e * 64 + fq * 16);
    }
#pragma unroll
    for (int i = 0; i < 2; ++i) {
      int ra = rg * 32 + i * 16 + fr;
      short8 af = *(const short8*)(qa + ra * 512 +
                                   ((h * 64 + fq * 16) ^ ((ra & 7) << 4)));
#pragma unroll
      for (int j = 0; j < 2; ++j) {
        sacc[h2][i][j] = __builtin_amdgcn_mfma_f32_16x16x32_bf16(
            af, bhi[j], sacc[h2][i][j], 0, 0, 0);
        sacc[h2][i][j] = __builtin_amdgcn_mfma_f32_16x16x32_bf16(
            af, blo[j], sacc[h2][i][j], 0, 0, 0);
      }
    }
  }
  __syncthreads();

#pragma unroll
  for (int h2 = 0; h2 < 2; ++h2) {
    int h = hg * 2 + h2;
#pragma unroll
    for (int i = 0; i < 2; ++i)
#pragma unroll
      for (int j = 0; j < 2; ++j)
#pragma unroll
        for (int reg = 0; reg < 4; ++reg) {
          int r = rg * 32 + i * 16 + fq * 4 + reg;
          int e = j * 16 + fr;
          float v = sacc[h2][i][j][reg] * Dinv_s[r][h];
          *(unsigned short*)(qa + r * 512 +
                             ((h * 64 + e * 2) ^ ((r & 7) << 4))) = f2bf(v);
        }
  }

  auto stage_wp = [&](int q, unsigned char* buf) {
#pragma unroll
    for (int i = 0; i < 2; ++i) {
      int seg = w * 2 + i;
      int rloc = seg * 2 + (lane >> 5);
      gload16((const char*)wpb + (size_t)(q * 32 + rloc) * 512 +
                  (((lane & 31) * 16) ^ ((rloc & 7) << 4)),
              buf + seg * 1024);
    }
  };
  stage_wp(0, wpS[0]);
  __syncthreads();

  const int rw = w >> 1, cw = w & 1;
  const int ra2 = rw * 16 + fr;
  const int sra2 = (ra2 & 7) << 4;
  for (int q = 0; q < 8; ++q) {
    if (q < 7) stage_wp(q + 1, wpS[(q + 1) & 1]);
    const unsigned char* wbuf = wpS[q & 1];
    f32x4 oacc = {0.f, 0.f, 0.f, 0.f};
#pragma unroll
    for (int ks = 0; ks < 8; ++ks) {
      short8 af = *(const short8*)(qa + ra2 * 512 + ((ks * 64 + fq * 16) ^ sra2));
      int rb = cw * 16 + fr;
      short8 wf = *(const short8*)(wbuf + rb * 512 +
                                   ((ks * 64 + fq * 16) ^ ((rb & 7) << 4)));
      oacc = __builtin_amdgcn_mfma_f32_16x16x32_bf16(af, wf, oacc, 0, 0, 0);
    }
    float bj = bias[q * 32 + cw * 16 + fr];
    float* orow = out + row0 * 256 + (size_t)(rw * 16 + fq * 4) * 256 +
                  q * 32 + cw * 16 + fr;
#pragma unroll
    for (int reg = 0; reg < 4; ++reg) orow[reg * 256] = oacc[reg] + bj;
    __syncthreads();
  }
}

// ---------------------------------------------------------------------------
extern "C" void kernel_launch(void* const* d_in, const int* in_sizes, int n_in,
                              void* d_out, int out_size, void* d_ws, size_t ws_size,
                              hipStream_t stream) {
  const float* x = (const float*)d_in[0];
  const float* Wq = (const float*)d_in[1];
  const float* Wkv = (const float*)d_in[2];
  const float* Wproj = (const float*)d_in[3];
  const float* bproj = (const float*)d_in[4];
  float* out = (float*)d_out;

  char* ws = (char*)d_ws;
  unsigned short* Q = (unsigned short*)(ws);                  // 67,108,864
  unsigned short* wcat = (unsigned short*)(ws + 67108864);    // 393,216
  unsigned short* wpb = (unsigned short*)(ws + 67502080);     // 131,072
  float* pctx = (float*)(ws + 67633152);                      // 33,554,432
  float* pksum = (float*)(ws + 101187584);                    // 1,048,576
  unsigned short* ctxT = (unsigned short*)(ws + 102236160);   // 262,144
  float* ksum = (float*)(ws + 102498304);                     // 8,192

  prep_w<<<1024, 256, 0, stream>>>(Wq, Wkv, Wproj, wcat, wpb);
  qkv_ctx<<<1024, 512, 0, stream>>>(x, wcat, Q, pctx, pksum);
  ctx_final2<<<64, 256, 0, stream>>>(pctx, pksum, ctxT, ksum);
  attn_proj<<<2048, 512, 0, stream>>>(Q, ctxT, ksum, wpb, bproj, out);
}

// Round 21
// 170.876 us; speedup vs baseline: 1.5322x; 1.0169x over previous
//
#include <hip/hip_runtime.h>
#include <hip/hip_bf16.h>
#include <cstdint>
#include <cstddef>

typedef __attribute__((ext_vector_type(8))) short short8;
typedef __attribute__((ext_vector_type(4))) float f32x4;

#define DEVI static __device__ __forceinline__

// f32 -> bf16 RTNE via the HIP intrinsic (compiler may emit native
// v_cvt_pk_bf16_f32; m240: scalar cast beats hand-written asm).
DEVI unsigned short f2bf(float f) {
  __hip_bfloat16 h = __float2bfloat16(f);
  return *reinterpret_cast<unsigned short*>(&h);
}
DEVI float bf2f(unsigned short s) {
  return __uint_as_float(((unsigned)s) << 16);
}
DEVI unsigned pack2(float a, float b) {
  return (unsigned)f2bf(a) | ((unsigned)f2bf(b) << 16);
}

DEVI void gload16(const void* g, void* l) {
  __builtin_amdgcn_global_load_lds(
      (__attribute__((address_space(1))) void*)g,
      (__attribute__((address_space(3))) void*)l, 16, 0, 0);
}

// ---------------------------------------------------------------------------
// prep_w: Wq/Wkv -> wcat bf16 [768][256], Wproj -> wpb bf16 [256][256]
// ---------------------------------------------------------------------------
__global__ __launch_bounds__(256) void prep_w(
    const float* __restrict__ Wq, const float* __restrict__ Wkv,
    const float* __restrict__ Wp, unsigned short* __restrict__ wcat,
    unsigned short* __restrict__ wpb) {
  int i = blockIdx.x * 256 + threadIdx.x;
  if (i < 196608) {
    float v = (i < 65536) ? Wq[i] : Wkv[i - 65536];
    wcat[i] = f2bf(v);
  } else {
    int j = i - 196608;
    wpb[j] = f2bf(Wp[j]);
  }
}

// ---------------------------------------------------------------------------
// qkv_ctx v4.3 (round-16/18/20 proven, 113 us): 1024 blocks x 512 thr
// (8 waves = 4 row-groups x 2 col-groups), 128 rows/block. xfc[2][8]/wave.
// 24 W-slivers (32 rows) ping-pong gload_lds; K/V phase 2 barriers/head;
// ksum on waves 4-5. LDS 48KB. VGPR 64 (launch_bounds 512,4).
// ---------------------------------------------------------------------------
__global__ __launch_bounds__(512, 4) void qkv_ctx(
    const float* __restrict__ x, const unsigned short* __restrict__ wcat,
    unsigned short* __restrict__ Q, float* __restrict__ pctx,
    float* __restrict__ pksum) {
  const int t = threadIdx.x;
  const int lane = t & 63, w = t >> 6;  // 8 waves
  const int wr = w >> 1, wc = w & 1;    // 4 x 2
  const int blk = blockIdx.x;           // 1024 blocks of 128 rows
  const size_t row0 = (size_t)blk * 128;
  const int fr = lane & 15, fq = lane >> 4;

  __shared__ __align__(16) unsigned char smem[49152];
  unsigned char* const wb0 = smem;           // 16KB [32][512B]
  unsigned char* const wb1 = smem + 16384;   // 16KB
  unsigned char* const kT = smem + 32768;    // 8KB [32 d][256B] ^((d&7)<<4)
  unsigned char* const vT = smem + 40960;    // 8KB

  const short ob = (short)0x3F80;
  const short8 ones = {ob, ob, ob, ob, ob, ob, ob, ob};

  // ---- x fragments direct to registers: rows wr*32 + i*16 + fr ----
  short8 xfc[2][8];
#pragma unroll
  for (int i = 0; i < 2; ++i) {
    const float* xr = x + (row0 + wr * 32 + i * 16 + fr) * 256;
#pragma unroll
    for (int ks = 0; ks < 8; ++ks) {
      float4 a = *(const float4*)(xr + ks * 32 + fq * 8);
      float4 b2 = *(const float4*)(xr + ks * 32 + fq * 8 + 4);
      union { unsigned u[4]; short8 s; } cv;
      cv.u[0] = pack2(a.x, a.y);
      cv.u[1] = pack2(a.z, a.w);
      cv.u[2] = pack2(b2.x, b2.y);
      cv.u[3] = pack2(b2.z, b2.w);
      xfc[i][ks] = cv.s;
    }
  }

  const int segr = lane >> 5;
  const int segc = (lane & 31) * 16;
  auto stage_w = [&](unsigned char* buf, int s) {
    int wr0 = (s < 8) ? s * 32
                      : (((s & 1) == 0) ? 256 + ((s - 8) >> 1) * 32
                                        : 512 + ((s - 8) >> 1) * 32);
#pragma unroll
    for (int i = 0; i < 2; ++i) {
      int seg = w * 2 + i;
      int rloc = seg * 2 + segr;
      gload16((const char*)wcat + (size_t)(wr0 + rloc) * 512 +
                  (segc ^ ((rloc & 7) << 4)),
              buf + seg * 1024);
    }
  };

  // ctx: waves 0-3 (dp = w>>1, ep = w&1); 4 ks steps over 128 n
  auto ctx_head = [&](int h) {
    if (w < 4) {
      const int dp = w >> 1, ep = w & 1;
      f32x4 cacc = {0.f, 0.f, 0.f, 0.f};
      const int rka = dp * 16 + fr;
      const int rkb = ep * 16 + fr;
#pragma unroll
      for (int ks = 0; ks < 4; ++ks) {
        short8 ak = *(const short8*)(kT + rka * 256 +
                                     ((ks * 64 + fq * 16) ^ ((rka & 7) << 4)));
        short8 bv = *(const short8*)(vT + rkb * 256 +
                                     ((ks * 64 + fq * 16) ^ ((rkb & 7) << 4)));
        cacc = __builtin_amdgcn_mfma_f32_16x16x32_bf16(ak, bv, cacc, 0, 0, 0);
      }
      float* pc = pctx + ((size_t)(blk * 8 + h)) * 1024;
#pragma unroll
      for (int reg = 0; reg < 4; ++reg) {
        int d = dp * 16 + fq * 4 + reg;
        int e = ep * 16 + fr;
        pc[d * 32 + e] = cacc[reg];
      }
    }
  };

  // ksum: waves 4-5 (dp = w&1), ones-MFMA on kT
  auto ksum_head = [&](int h) {
    if ((w >> 1) == 2) {
      const int dp = w & 1;
      f32x4 sacc = {0.f, 0.f, 0.f, 0.f};
      const int rka = dp * 16 + fr;
#pragma unroll
      for (int ks = 0; ks < 4; ++ks) {
        short8 ak = *(const short8*)(kT + rka * 256 +
                                     ((ks * 64 + fq * 16) ^ ((rka & 7) << 4)));
        sacc = __builtin_amdgcn_mfma_f32_16x16x32_bf16(ak, ones, sacc, 0, 0, 0);
      }
      if (fr == 0) {
#pragma unroll
        for (int reg = 0; reg < 4; ++reg) {
          int d = dp * 16 + fq * 4 + reg;
          pksum[((size_t)(blk * 8 + h)) * 32 + d] = sacc[reg];
        }
      }
    }
  };

  stage_w(wb0, 0);
  __syncthreads();

  unsigned char* const bb = kT + w * 1536;  // wave-private bounce [32][48B]

  // ================= Q phase: slivers 0..7 =================
#pragma unroll
  for (int s = 0; s < 8; ++s) {
    stage_w((s & 1) ? wb0 : wb1, s + 1);
    const unsigned char* wbuf = (s & 1) ? wb1 : wb0;

    f32x4 acc[2] = {{0.f, 0.f, 0.f, 0.f}, {0.f, 0.f, 0.f, 0.f}};
    const int rb = wc * 16 + fr;
    const int swb = (rb & 7) << 4;
#pragma unroll
    for (int ks = 0; ks < 8; ++ks) {
      short8 wf = *(const short8*)(wbuf + rb * 512 + ((ks * 64 + fq * 16) ^ swb));
      acc[0] = __builtin_amdgcn_mfma_f32_16x16x32_bf16(wf, xfc[0][ks], acc[0], 0, 0, 0);
      acc[1] = __builtin_amdgcn_mfma_f32_16x16x32_bf16(wf, xfc[1][ks], acc[1], 0, 0, 0);
    }
    // lane holds Q[x-row wr*32+i*16+fr][col s*32 + wc*16 + fq*4 + 0..3]
#pragma unroll
    for (int i = 0; i < 2; ++i) {
      float v0 = acc[i][0], v1 = acc[i][1], v2 = acc[i][2], v3 = acc[i][3];
      v0 = (v0 > 0.f) ? (v0 + 1.f) : __expf(v0);
      v1 = (v1 > 0.f) ? (v1 + 1.f) : __expf(v1);
      v2 = (v2 > 0.f) ? (v2 + 1.f) : __expf(v2);
      v3 = (v3 > 0.f) ? (v3 + 1.f) : __expf(v3);
      uint2 pk;
      pk.x = pack2(v0, v1);
      pk.y = pack2(v2, v3);
      *(uint2*)(bb + (i * 16 + fr) * 48 + fq * 8) = pk;
    }
    {
      int rowq = lane >> 1, ch = lane & 1;
      uint4 u = *(const uint4*)(bb + rowq * 48 + ch * 16);
      *(uint4*)((char*)Q + (row0 + wr * 32 + rowq) * 512 + s * 64 + wc * 32 +
                ch * 16) = u;
    }
    __syncthreads();
  }

  // ================= K/V phase: heads 0..7 (2 barriers/head) =============
#pragma unroll
  for (int h = 0; h < 8; ++h) {
    const int sk = 8 + 2 * h;
    // ---- K sliver (wb0) ----
    stage_w(wb1, sk + 1);  // V head h
    f32x4 kacc[2] = {{0.f, 0.f, 0.f, 0.f}, {0.f, 0.f, 0.f, 0.f}};
    {
      const int rb = wc * 16 + fr;
      const int swb = (rb & 7) << 4;
#pragma unroll
      for (int ks = 0; ks < 8; ++ks) {
        short8 wf = *(const short8*)(wb0 + rb * 512 + ((ks * 64 + fq * 16) ^ swb));
        kacc[0] = __builtin_amdgcn_mfma_f32_16x16x32_bf16(xfc[0][ks], wf, kacc[0], 0, 0, 0);
        kacc[1] = __builtin_amdgcn_mfma_f32_16x16x32_bf16(xfc[1][ks], wf, kacc[1], 0, 0, 0);
      }
    }
    if (h > 0) {
      ctx_head(h - 1);   // waves 0-3: reads kT/vT of head h-1
      ksum_head(h - 1);  // waves 4-5: reads kT of head h-1
    }
    __syncthreads();  // #1: ctx/ksum reads done; V staged; wb0 reads done

    // kT write: d = wc*16+fr, n = wr*32 + i*16 + fq*4 + 0..3 (elu)
#pragma unroll
    for (int i = 0; i < 2; ++i) {
      int d = wc * 16 + fr;
      float v0 = kacc[i][0], v1 = kacc[i][1], v2 = kacc[i][2], v3 = kacc[i][3];
      v0 = (v0 > 0.f) ? (v0 + 1.f) : __expf(v0);
      v1 = (v1 > 0.f) ? (v1 + 1.f) : __expf(v1);
      v2 = (v2 > 0.f) ? (v2 + 1.f) : __expf(v2);
      v3 = (v3 > 0.f) ? (v3 + 1.f) : __expf(v3);
      uint2 pk;
      pk.x = pack2(v0, v1);
      pk.y = pack2(v2, v3);
      int nb = wr * 64 + i * 32 + fq * 8;  // byte offset = n*2
      *(uint2*)(kT + d * 256 + (nb ^ ((d & 7) << 4))) = pk;
    }

    // ---- V sliver (wb1) ----
    if (h < 7) stage_w(wb0, sk + 2);  // K head h+1
    f32x4 vacc[2] = {{0.f, 0.f, 0.f, 0.f}, {0.f, 0.f, 0.f, 0.f}};
    {
      const int rb = wc * 16 + fr;
      const int swb = (rb & 7) << 4;
#pragma unroll
      for (int ks = 0; ks < 8; ++ks) {
        short8 wf = *(const short8*)(wb1 + rb * 512 + ((ks * 64 + fq * 16) ^ swb));
        vacc[0] = __builtin_amdgcn_mfma_f32_16x16x32_bf16(xfc[0][ks], wf, vacc[0], 0, 0, 0);
        vacc[1] = __builtin_amdgcn_mfma_f32_16x16x32_bf16(xfc[1][ks], wf, vacc[1], 0, 0, 0);
      }
    }
    // vT write: prev readers (ctx_head(h-1)) completed before barrier #1
#pragma unroll
    for (int i = 0; i < 2; ++i) {
      int e = wc * 16 + fr;
      uint2 pk;
      pk.x = pack2(vacc[i][0], vacc[i][1]);
      pk.y = pack2(vacc[i][2], vacc[i][3]);
      int nb = wr * 64 + i * 32 + fq * 8;
      *(uint2*)(vT + e * 256 + (nb ^ ((e & 7) << 4))) = pk;
    }
    __syncthreads();  // #2: kT+vT visible; stages drained
  }
  ctx_head(7);
  ksum_head(7);
}

// ---------------------------------------------------------------------------
// ctx_final2: reduce 128 block-partials per (b,h) -> ctxT bf16 hi/lo + ksum
// ---------------------------------------------------------------------------
__global__ __launch_bounds__(256) void ctx_final2(
    const float* __restrict__ pctx, const float* __restrict__ pksum,
    unsigned short* __restrict__ ctxT, float* __restrict__ ksum) {
  int bh = blockIdx.x;
  int b = bh >> 3, h = bh & 7;
  int t = threadIdx.x;
  int d = t >> 3, e4 = (t & 7) * 4;
  float s[4] = {0.f, 0.f, 0.f, 0.f};
  for (int pp = 0; pp < 128; ++pp) {
    const float* q = pctx + ((size_t)((b * 128 + pp) * 8 + h)) * 1024 + d * 32 + e4;
    s[0] += q[0]; s[1] += q[1]; s[2] += q[2]; s[3] += q[3];
  }
  unsigned short* cc = ctxT + (size_t)bh * 2048;
#pragma unroll
  for (int e2 = 0; e2 < 4; ++e2) {
    int e = e4 + e2;
    unsigned short hi = f2bf(s[e2]);
    float lo = s[e2] - bf2f(hi);
    cc[e * 32 + d] = hi;
    cc[1024 + e * 32 + d] = f2bf(lo);
  }
  __shared__ float ksp[8][32];
  int d2 = t & 31, ch = t >> 5;
  float ss = 0.f;
  for (int pp = ch; pp < 128; pp += 8)
    ss += pksum[((size_t)((b * 128 + pp) * 8 + h)) * 32 + d2];
  ksp[ch][d2] = ss;
  __syncthreads();
  if (t < 32) {
    float r = 0.f;
#pragma unroll
    for (int c = 0; c < 8; ++c) r += ksp[c][t];
    ksum[bh * 32 + t] = r;
  }
}

// ---------------------------------------------------------------------------
// attn_proj (round-12/13 proven, unchanged): 2048 blocks (64-row panels),
// 512 thr, 68.6KB LDS -> 2 blocks/CU.
// ---------------------------------------------------------------------------
__global__ __launch_bounds__(512) void attn_proj(
    const unsigned short* __restrict__ Q,
    const unsigned short* __restrict__ ctxT,
    const float* __restrict__ ksum,
    const unsigned short* __restrict__ wpb,
    const float* __restrict__ bias,
    float* __restrict__ out) {
  const int t = threadIdx.x;
  const int lane = t & 63, w = t >> 6;  // 8 waves
  const int panel = blockIdx.x;         // 2048
  const int b = panel >> 8;
  const size_t row0 = (size_t)panel * 64;
  const int fr = lane & 15, fq = lane >> 4;

  __shared__ __align__(16) unsigned char qa[32768];      // [64][512B] swz
  __shared__ __align__(16) unsigned char wpS[2][16384];  // ping-pong W stages
  __shared__ float ksumL[256];
  __shared__ float Dinv_s[64][8];

#pragma unroll
  for (int s = 0; s < 4; ++s) {
    int seg = w * 4 + s;
    int row = seg * 2 + (lane >> 5);
    gload16((const char*)Q + (row0 + row) * 512 +
                (((lane & 31) * 16) ^ ((row & 7) << 4)),
            qa + seg * 1024);
  }
  if (w == 0) gload16((const char*)(ksum + b * 256) + lane * 16, (void*)ksumL);
  __syncthreads();

  {
    int r = t >> 3, h = t & 7;
    const unsigned char* qrow = qa + r * 512;
    int swzr = (r & 7) << 4;
    float s = 0.f;
#pragma unroll
    for (int dd = 0; dd < 16; ++dd) {
      unsigned u = *(const unsigned*)(qrow + ((h * 64 + dd * 4) ^ swzr));
      s += __uint_as_float(u << 16) * ksumL[h * 32 + dd * 2] +
           __uint_as_float(u & 0xffff0000u) * ksumL[h * 32 + dd * 2 + 1];
    }
    Dinv_s[r][h] = 1.f / fmaxf(s, 1e-6f);
  }

  const int rg = w >> 2, hg = w & 3;
  f32x4 sacc[2][2][2];
#pragma unroll
  for (int h2 = 0; h2 < 2; ++h2)
#pragma unroll
    for (int i = 0; i < 2; ++i)
#pragma unroll
      for (int j = 0; j < 2; ++j)
#pragma unroll
        for (int c = 0; c < 4; ++c) sacc[h2][i][j][c] = 0.f;

#pragma unroll
  for (int h2 = 0; h2 < 2; ++h2) {
    int h = hg * 2 + h2;
    const char* cbh = (const char*)ctxT + ((size_t)(b * 8 + h)) * 4096;
    short8 bhi[2], blo[2];
#pragma unroll
    for (int j = 0; j < 2; ++j) {
      int e = j * 16 + fr;
      bhi[j] = *(const short8*)(cbh + e * 64 + fq * 16);
      blo[j] = *(const short8*)(cbh + 2048 + e * 64 + fq * 16);
    }
#pragma unroll
    for (int i = 0; i < 2; ++i) {
      int ra = rg * 32 + i * 16 + fr;
      short8 af = *(const short8*)(qa + ra * 512 +
                                   ((h * 64 + fq * 16) ^ ((ra & 7) << 4)));
#pragma unroll
      for (int j = 0; j < 2; ++j) {
        sacc[h2][i][j] = __builtin_amdgcn_mfma_f32_16x16x32_bf16(
            af, bhi[j], sacc[h2][i][j], 0, 0, 0);
        sacc[h2][i][j] = __builtin_amdgcn_mfma_f32_16x16x32_bf16(
            af, blo[j], sacc[h2][i][j], 0, 0, 0);
      }
    }
  }
  __syncthreads();

#pragma unroll
  for (int h2 = 0; h2 < 2; ++h2) {
    int h = hg * 2 + h2;
#pragma unroll
    for (int i = 0; i < 2; ++i)
#pragma unroll
      for (int j = 0; j < 2; ++j)
#pragma unroll
        for (int reg = 0; reg < 4; ++reg) {
          int r = rg * 32 + i * 16 + fq * 4 + reg;
          int e = j * 16 + fr;
          float v = sacc[h2][i][j][reg] * Dinv_s[r][h];
          *(unsigned short*)(qa + r * 512 +
                             ((h * 64 + e * 2) ^ ((r & 7) << 4))) = f2bf(v);
        }
  }

  auto stage_wp = [&](int q, unsigned char* buf) {
#pragma unroll
    for (int i = 0; i < 2; ++i) {
      int seg = w * 2 + i;
      int rloc = seg * 2 + (lane >> 5);
      gload16((const char*)wpb + (size_t)(q * 32 + rloc) * 512 +
                  (((lane & 31) * 16) ^ ((rloc & 7) << 4)),
              buf + seg * 1024);
    }
  };
  stage_wp(0, wpS[0]);
  __syncthreads();

  const int rw = w >> 1, cw = w & 1;
  const int ra2 = rw * 16 + fr;
  const int sra2 = (ra2 & 7) << 4;
  for (int q = 0; q < 8; ++q) {
    if (q < 7) stage_wp(q + 1, wpS[(q + 1) & 1]);
    const unsigned char* wbuf = wpS[q & 1];
    f32x4 oacc = {0.f, 0.f, 0.f, 0.f};
#pragma unroll
    for (int ks = 0; ks < 8; ++ks) {
      short8 af = *(const short8*)(qa + ra2 * 512 + ((ks * 64 + fq * 16) ^ sra2));
      int rb = cw * 16 + fr;
      short8 wf = *(const short8*)(wbuf + rb * 512 +
                                   ((ks * 64 + fq * 16) ^ ((rb & 7) << 4)));
      oacc = __builtin_amdgcn_mfma_f32_16x16x32_bf16(af, wf, oacc, 0, 0, 0);
    }
    float bj = bias[q * 32 + cw * 16 + fr];
    float* orow = out + row0 * 256 + (size_t)(rw * 16 + fq * 4) * 256 +
                  q * 32 + cw * 16 + fr;
#pragma unroll
    for (int reg = 0; reg < 4; ++reg) orow[reg * 256] = oacc[reg] + bj;
    __syncthreads();
  }
}

// ---------------------------------------------------------------------------
extern "C" void kernel_launch(void* const* d_in, const int* in_sizes, int n_in,
                              void* d_out, int out_size, void* d_ws, size_t ws_size,
                              hipStream_t stream) {
  const float* x = (const float*)d_in[0];
  const float* Wq = (const float*)d_in[1];
  const float* Wkv = (const float*)d_in[2];
  const float* Wproj = (const float*)d_in[3];
  const float* bproj = (const float*)d_in[4];
  float* out = (float*)d_out;

  char* ws = (char*)d_ws;
  unsigned short* Q = (unsigned short*)(ws);                  // 67,108,864
  unsigned short* wcat = (unsigned short*)(ws + 67108864);    // 393,216
  unsigned short* wpb = (unsigned short*)(ws + 67502080);     // 131,072
  float* pctx = (float*)(ws + 67633152);                      // 33,554,432
  float* pksum = (float*)(ws + 101187584);                    // 1,048,576
  unsigned short* ctxT = (unsigned short*)(ws + 102236160);   // 262,144
  float* ksum = (float*)(ws + 102498304);                     // 8,192

  prep_w<<<1024, 256, 0, stream>>>(Wq, Wkv, Wproj, wcat, wpb);
  qkv_ctx<<<1024, 512, 0, stream>>>(x, wcat, Q, pctx, pksum);
  ctx_final2<<<64, 256, 0, stream>>>(pctx, pksum, ctxT, ksum);
  attn_proj<<<2048, 512, 0, stream>>>(Q, ctxT, ksum, wpb, bproj, out);
}